// Round 6
// baseline (461.490 us; speedup 1.0000x reference)
//
#include <hip/hip_runtime.h>
#include <hip/hip_bf16.h>
#include <math.h>

typedef __hip_bfloat16 bf16;
typedef __attribute__((ext_vector_type(8))) short short8;
typedef __attribute__((ext_vector_type(4))) short short4v;
typedef __attribute__((ext_vector_type(4))) float f32x4;

#define MFMA16(a, b, c) __builtin_amdgcn_mfma_f32_16x16x32_bf16((a), (b), (c), 0, 0, 0)

typedef const __attribute__((address_space(1))) void GVOID;
typedef __attribute__((address_space(3))) void LVOID;

__device__ __forceinline__ float b2f(short s) {
    union { unsigned u; float f; } v;
    v.u = ((unsigned)(unsigned short)s) << 16;
    return v.f;
}
__device__ __forceinline__ short f2b(float f) {
    union { float f; unsigned u; } v;
    v.f = f;
    unsigned r = v.u + 0x7fffu + ((v.u >> 16) & 1u);
    return (short)(r >> 16);
}
__device__ __forceinline__ unsigned packbf(float a, float b) {
    return ((unsigned)(unsigned short)f2b(a)) | (((unsigned)(unsigned short)f2b(b)) << 16);
}

// ---------------------------------------------------------------------------
// Dtype sniffer (f32 confirmed; deterministic guard).
// ---------------------------------------------------------------------------
__global__ void sniff_kernel(const unsigned* __restrict__ X, int* __restrict__ flag) {
    __shared__ int cnt;
    if (threadIdx.x == 0) cnt = 0;
    __syncthreads();
    int c = 0;
    for (int i = threadIdx.x; i < 256; i += 64) {
        unsigned w = X[i];
        unsigned e = (w >> 7) & 0xFFu;
        c += (e > 140u) ? 1 : 0;
    }
    atomicAdd(&cnt, c);
    __syncthreads();
    if (threadIdx.x == 0) *flag = (cnt >= 16) ? 1 : 0;
}

__device__ __forceinline__ void canon8(const void* src, short* dst, int i, int f) {
    short8 o;
    if (f) {
        const float* s = (const float*)src + (size_t)i * 8;
#pragma unroll
        for (int j = 0; j < 8; ++j) o[j] = f2b(s[j]);
    } else {
        o = ((const short8*)src)[i];
    }
    ((short8*)dst)[i] = o;
}

__global__ __launch_bounds__(256) void canon_x_kernel(
    const void* __restrict__ src, short* __restrict__ dst, int n8,
    const int* __restrict__ flag)
{
    int i = blockIdx.x * 256 + threadIdx.x;
    if (i >= n8) return;
    canon8(src, dst, i, *flag);
}

__global__ __launch_bounds__(256) void canon_w4_kernel(
    const void* __restrict__ s0, const void* __restrict__ s1,
    const void* __restrict__ s2, const void* __restrict__ s3,
    short* __restrict__ d0, short* __restrict__ d1,
    short* __restrict__ d2, short* __restrict__ d3,
    const int* __restrict__ flag)
{
    const int m = blockIdx.y;
    const void* src = (m == 0) ? s0 : (m == 1) ? s1 : (m == 2) ? s2 : s3;
    short* dst = (m == 0) ? d0 : (m == 1) ? d1 : (m == 2) ? d2 : d3;
    int i = blockIdx.x * 256 + threadIdx.x;
    canon8(src, dst, i, *flag);
}

__global__ void canon_vec_kernel(
    const void* __restrict__ bq, const void* __restrict__ bk,
    const void* __restrict__ bv, const void* __restrict__ bo,
    const void* __restrict__ qw, const void* __restrict__ kw,
    float* __restrict__ biasqkv, float* __restrict__ boc,
    float* __restrict__ qwc, float* __restrict__ kwc,
    const int* __restrict__ flag)
{
    const int f = *flag;
    for (int i = threadIdx.x; i < 6336; i += 256) {
        const void* src; float* dst; int j;
        if (i < 4608) {
            int m = i / 1536; j = i - m * 1536;
            src = (m == 0) ? bq : (m == 1) ? bk : bv; dst = biasqkv + i;
        } else if (i < 6144) { j = i - 4608; src = bo; dst = boc + j; }
        else if (i < 6240)   { j = i - 6144; src = qw; dst = qwc + j; }
        else                 { j = i - 6240; src = kw; dst = kwc + j; }
        *dst = f ? ((const float*)src)[j] : b2f(((const short*)src)[j]);
    }
}

// ---------------------------------------------------------------------------
// RoPE tables: cos/sin [1024][96] fp32.
// ---------------------------------------------------------------------------
__global__ void rope_tables_kernel(float* __restrict__ cosT, float* __restrict__ sinT) {
    int idx = blockIdx.x * 256 + threadIdx.x;
    if (idx >= 1024 * 96) return;
    int p = idx / 96;
    int d = idx - p * 96;
    int r = p >> 5, c = p & 31;
    int inRow = (d < 48);
    int dd = inRow ? d : d - 48;
    float pos = inRow ? (float)r : (float)c;
    float ex = -(float)(dd & ~1) / 48.0f;
    float f = powf(10000.0f, ex);
    float ang = pos * f;
    cosT[idx] = cosf(ang);
    sinT[idx] = sinf(ang);
}

// ---------------------------------------------------------------------------
// 256x256 NT GEMM, BK=32, double-buffered (64KB LDS -> 2 blocks/CU so the
// per-tile vmcnt(0)+barrier drain is hidden by the other block). LDS swizzle
// S(byte)=byte^(((byte>>7)&3)<<4): linear gload_lds dest + inverse-swizzled
// global src + swizzled ds_read (per-lane constant since row bits1-2 = li
// bits1-2) -> 2-way banks (free) vs 8-way linear.
// ---------------------------------------------------------------------------
__global__ __launch_bounds__(512) void gemm256_kernel(
    const bf16* __restrict__ A, const bf16* __restrict__ Bw,
    const float* __restrict__ bias,
    bf16* __restrict__ O0, bf16* __restrict__ O1, bf16* __restrict__ O2,
    int K, const int* __restrict__ outFlag)
{
    __shared__ __align__(16) short As[2][256 * 32];
    __shared__ __align__(16) short Bs[2][256 * 32];

    const int tid = threadIdx.x;
    const int lane = tid & 63, w = tid >> 6;
    const int wm = w >> 2, wn = w & 3;
    const int li = lane & 15, lg = lane >> 4;

    const int total = gridDim.x * gridDim.y;
    const int pp = blockIdx.y * gridDim.x + blockIdx.x;
    const int lb = (pp & 7) * (total >> 3) + (pp >> 3);
    const int nb = lb % gridDim.x;
    const int mb = lb / gridDim.x;
    const long mBase = (long)mb * 256;
    const long nGlob = (long)nb * 256;

    // staging: linear LDS dest L, inverse-swizzled global source S
    const bf16* aSrc[2]; const bf16* bSrc[2]; int ldsOff[2];
#pragma unroll
    for (int u = 0; u < 2; ++u) {
        const int L = u * 8192 + tid * 16;          // byte in 16KB tile
        const int S = L ^ (((L >> 7) & 3) << 4);    // involution
        const int srow = S >> 6;
        const int scol = (S & 63) >> 1;             // shorts
        aSrc[u] = A + (mBase + srow) * K + scol;
        bSrc[u] = Bw + (nGlob + srow) * K + scol;
        ldsOff[u] = L >> 1;
    }
    // swizzled read offset (shorts): per-lane constant
    const int koff = ((lg * 16) ^ (((li >> 1) & 3) << 4)) >> 1;

    f32x4 acc[8][4] = {};
    const int NT = K >> 5;

    auto stage = [&](int tt, int bb) {
        const long kc = (long)tt * 32;
#pragma unroll
        for (int u = 0; u < 2; ++u)
            __builtin_amdgcn_global_load_lds((GVOID*)(aSrc[u] + kc),
                                             (LVOID*)&As[bb][ldsOff[u]], 16, 0, 0);
#pragma unroll
        for (int u = 0; u < 2; ++u)
            __builtin_amdgcn_global_load_lds((GVOID*)(bSrc[u] + kc),
                                             (LVOID*)&Bs[bb][ldsOff[u]], 16, 0, 0);
    };

    stage(0, 0);
    asm volatile("s_waitcnt vmcnt(0)" ::: "memory");
    __builtin_amdgcn_s_barrier();
    asm volatile("" ::: "memory");

    for (int t = 0; t < NT; ++t) {
        const int cb = t & 1;
        if (t + 1 < NT) stage(t + 1, cb ^ 1);
        const short* Ab = &As[cb][0];
        const short* Bb = &Bs[cb][0];
        short8 fb[4], fa[4];
#pragma unroll
        for (int n = 0; n < 4; ++n)
            fb[n] = *(const short8*)(Bb + (wn * 64 + n * 16 + li) * 32 + koff);
#pragma unroll
        for (int m = 0; m < 4; ++m)
            fa[m] = *(const short8*)(Ab + (wm * 128 + m * 16 + li) * 32 + koff);
        __builtin_amdgcn_sched_barrier(0);
        __builtin_amdgcn_s_setprio(1);
#pragma unroll
        for (int m = 0; m < 4; ++m)
#pragma unroll
            for (int n = 0; n < 4; ++n)
                acc[m][n] = MFMA16(fa[m], fb[n], acc[m][n]);
        __builtin_amdgcn_s_setprio(0);
        __builtin_amdgcn_sched_barrier(0);
#pragma unroll
        for (int m = 0; m < 4; ++m)
            fa[m] = *(const short8*)(Ab + (wm * 128 + 64 + m * 16 + li) * 32 + koff);
        __builtin_amdgcn_sched_barrier(0);
        __builtin_amdgcn_s_setprio(1);
#pragma unroll
        for (int m = 0; m < 4; ++m)
#pragma unroll
            for (int n = 0; n < 4; ++n)
                acc[4 + m][n] = MFMA16(fa[m], fb[n], acc[4 + m][n]);
        __builtin_amdgcn_s_setprio(0);
        __builtin_amdgcn_sched_barrier(0);
        asm volatile("s_waitcnt vmcnt(0)" ::: "memory");
        __builtin_amdgcn_s_barrier();
        asm volatile("" ::: "memory");
    }

    const int f32out = outFlag ? *outFlag : 0;
    const int mat = nb / 6;
    const long colBase = nGlob - (long)mat * 1536;
    bf16* Ob = (mat == 0) ? O0 : (mat == 1) ? O1 : O2;
    if (f32out) {
        float* Cf = (float*)Ob;
#pragma unroll
        for (int n = 0; n < 4; ++n) {
            const long col = colBase + wn * 64 + n * 16 + li;
            const float bv = bias[nGlob + wn * 64 + n * 16 + li];
#pragma unroll
            for (int m = 0; m < 8; ++m) {
                const long row = mBase + wm * 128 + m * 16 + lg * 4;
#pragma unroll
                for (int i = 0; i < 4; ++i)
                    Cf[(row + i) * 1536 + col] = acc[m][n][i] + bv;
            }
        }
    } else {
#pragma unroll
        for (int n = 0; n < 4; ++n) {
            const long col = colBase + wn * 64 + n * 16 + li;
            const float bv = bias[nGlob + wn * 64 + n * 16 + li];
#pragma unroll
            for (int m = 0; m < 8; ++m) {
                const long row = mBase + wm * 128 + m * 16 + lg * 4;
#pragma unroll
                for (int i = 0; i < 4; ++i)
                    Ob[(row + i) * 1536 + col] = __float2bfloat16(acc[m][n][i] + bv);
            }
        }
    }
}

// ---------------------------------------------------------------------------
// Fused per-head RMSNorm + RoPE, in place (scale folds 1/sqrt(96), +log2e for Q).
// ---------------------------------------------------------------------------
__global__ __launch_bounds__(256) void norm_rope_kernel(
    bf16* __restrict__ T, const float* __restrict__ wgt,
    const float* __restrict__ cosT, const float* __restrict__ sinT,
    float scale)
{
    const int row = blockIdx.x * 256 + threadIdx.x;
    const int tok = row >> 4;
    const int h = row & 15;
    const int spos = tok & 1023;
    bf16* p = T + (size_t)tok * 1536 + h * 96;

    float x[96];
#pragma unroll
    for (int v = 0; v < 12; ++v) {
        short8 t = *(const short8*)(p + v * 8);
#pragma unroll
        for (int j = 0; j < 8; ++j) x[v * 8 + j] = b2f(t[j]);
    }
    float ss = 0.f;
#pragma unroll
    for (int d = 0; d < 96; ++d) ss += x[d] * x[d];
    const float rn = scale / sqrtf(ss * (1.0f / 96.0f) + 1e-6f);

    const float* cr = cosT + spos * 96;
    const float* sr = sinT + spos * 96;

#pragma unroll
    for (int v = 0; v < 12; ++v) {
        short8 o;
#pragma unroll
        for (int j = 0; j < 8; j += 2) {
            const int d = v * 8 + j;
            const float x0 = x[d] * rn * wgt[d];
            const float x1 = x[d + 1] * rn * wgt[d + 1];
            o[j]     = f2b(x0 * cr[d] - x1 * sr[d]);
            o[j + 1] = f2b(x1 * cr[d + 1] + x0 * sr[d + 1]);
        }
        *(short8*)(p + v * 8) = o;
    }
}

// ---------------------------------------------------------------------------
// Flash attention, swapped-operand form. Block = (b,h) x 128 Q rows
// (4 waves x 32). S^T = mfma(K,Q): q is lane-local (col=li) -> softmax is
// 15 in-lane fmax + 2 shuffles, stats per-lane. O^T = mfma(V^T,P): col=q=li
// -> alpha/l used directly, packed 8B output stores. T14 async-STAGE:
// K/V global->reg issued right after LDS-write barrier, covered by compute.
// log2-domain scores (log2e folded into Q); defer-max THR=8.
// ---------------------------------------------------------------------------
__global__ __launch_bounds__(256) void attn_kernel(
    const bf16* __restrict__ Q, const bf16* __restrict__ K,
    const bf16* __restrict__ V, bf16* __restrict__ O)
{
    __shared__ __align__(16) short Ks[64 * 100];
    __shared__ __align__(16) short Vt[96 * 76];
    __shared__ __align__(16) short Pl[4][32 * 72];

    const int tid = threadIdx.x;
    const int l = tid & 63, w = tid >> 6;
    const int li = l & 15, lg = l >> 4;

    const int p = blockIdx.x;
    const int lb = (p & 7) * 128 + (p >> 3);
    const int qt = lb & 7;
    const int bh = lb >> 3;
    const int b = bh >> 4, h = bh & 15;
    const size_t tokBase = (size_t)b * 1024;

    // Q fragments (B-operand: row=q=li, k=kk*32+lg*8)
    short8 aq[2][3];
#pragma unroll
    for (int r = 0; r < 2; ++r) {
        const bf16* qp = Q + (tokBase + qt * 128 + w * 32 + r * 16 + li) * 1536 + h * 96;
#pragma unroll
        for (int kk = 0; kk < 3; ++kk)
            aq[r][kk] = *(const short8*)(qp + kk * 32 + lg * 8);
    }

    float m_r[2] = {-1e30f, -1e30f};
    float l_r[2] = {0.f, 0.f};
    f32x4 o[2][6] = {};

    int kr[3], km[3];
#pragma unroll
    for (int u = 0; u < 3; ++u) {
        const int c = tid + 256 * u;
        kr[u] = c / 12;
        km[u] = (c - kr[u] * 12) * 8;
    }
    const int vr = tid >> 2;
    const int vc0 = (tid & 3) * 24;
    short* Plw = &Pl[w][0];

    // T14 prologue: tile 0 into regs
    short8 kreg[3], vreg[3];
#pragma unroll
    for (int u = 0; u < 3; ++u)
        kreg[u] = *(const short8*)(K + (tokBase + kr[u]) * 1536 + h * 96 + km[u]);
    {
        const bf16* vp = V + (tokBase + vr) * 1536 + h * 96 + vc0;
#pragma unroll
        for (int u = 0; u < 3; ++u) vreg[u] = *(const short8*)(vp + u * 8);
    }

    for (int t0 = 0; t0 < 1024; t0 += 64) {
        __syncthreads();   // prior tile's LDS reads done
        // reg -> LDS
#pragma unroll
        for (int u = 0; u < 3; ++u)
            *(short8*)&Ks[kr[u] * 100 + km[u]] = kreg[u];
#pragma unroll
        for (int u = 0; u < 3; ++u)
#pragma unroll
            for (int j = 0; j < 8; ++j)
                Vt[(vc0 + u * 8 + j) * 76 + vr] = vreg[u][j];
        __syncthreads();

        // issue next tile's global loads (covered by compute below)
        const int t1 = (t0 + 64 < 1024) ? t0 + 64 : t0;
#pragma unroll
        for (int u = 0; u < 3; ++u)
            kreg[u] = *(const short8*)(K + (tokBase + t1 + kr[u]) * 1536 + h * 96 + km[u]);
        {
            const bf16* vp = V + (tokBase + t1 + vr) * 1536 + h * 96 + vc0;
#pragma unroll
            for (int u = 0; u < 3; ++u) vreg[u] = *(const short8*)(vp + u * 8);
        }

        // S^T[key][q]: key = kn*16+lg*4+i (rows), q = li (cols)
        f32x4 s4[2][4] = {};
#pragma unroll
        for (int kk = 0; kk < 3; ++kk) {
            short8 fk[4];
#pragma unroll
            for (int kn = 0; kn < 4; ++kn)
                fk[kn] = *(const short8*)&Ks[(kn * 16 + li) * 100 + kk * 32 + lg * 8];
#pragma unroll
            for (int r = 0; r < 2; ++r)
#pragma unroll
                for (int kn = 0; kn < 4; ++kn)
                    s4[r][kn] = MFMA16(fk[kn], aq[r][kk], s4[r][kn]);
        }

        // softmax: per lane, 16 local keys; cross-lg reduce via xor 16/32
#pragma unroll
        for (int r = 0; r < 2; ++r) {
            float mk[4];
#pragma unroll
            for (int kn = 0; kn < 4; ++kn)
                mk[kn] = fmaxf(fmaxf(s4[r][kn][0], s4[r][kn][1]),
                               fmaxf(s4[r][kn][2], s4[r][kn][3]));
            float pm = fmaxf(fmaxf(mk[0], mk[1]), fmaxf(mk[2], mk[3]));
            pm = fmaxf(pm, __shfl_xor(pm, 16));
            pm = fmaxf(pm, __shfl_xor(pm, 32));

            float alpha = 1.0f;
            const bool need = (pm > m_r[r] + 8.0f);
            if (need) { alpha = exp2f(m_r[r] - pm); m_r[r] = pm; }
            const float mn = m_r[r];

            float rs = 0.f;
            unsigned pw[8];
#pragma unroll
            for (int kn = 0; kn < 4; ++kn) {
                float p0 = exp2f(s4[r][kn][0] - mn);
                float p1 = exp2f(s4[r][kn][1] - mn);
                float p2 = exp2f(s4[r][kn][2] - mn);
                float p3 = exp2f(s4[r][kn][3] - mn);
                rs += (p0 + p1) + (p2 + p3);
                pw[kn * 2]     = packbf(p0, p1);
                pw[kn * 2 + 1] = packbf(p2, p3);
            }
            rs += __shfl_xor(rs, 16);
            rs += __shfl_xor(rs, 32);
            l_r[r] = l_r[r] * alpha + rs;
            if (need) {
#pragma unroll
                for (int dn = 0; dn < 6; ++dn)
#pragma unroll
                    for (int i = 0; i < 4; ++i) o[r][dn][i] *= alpha;
            }
            // P[q=li][k] packed b32 writes
            unsigned* Pw = (unsigned*)Plw;
            const int rowW = ((r * 16 + li) * 72) >> 1;
#pragma unroll
            for (int kn = 0; kn < 4; ++kn) {
#pragma unroll
                for (int ip = 0; ip < 2; ++ip)
                    Pw[rowW + ((kn * 16 + lg * 4 + ip * 2) >> 1)] = pw[kn * 2 + ip];
            }
        }

        // O^T += V^T * P^T : fa = V^T rows (d), fb = P rows (q)
#pragma unroll
        for (int kt = 0; kt < 2; ++kt) {
            short8 pa[2];
#pragma unroll
            for (int r = 0; r < 2; ++r)
                pa[r] = *(const short8*)&Plw[(r * 16 + li) * 72 + kt * 32 + lg * 8];
#pragma unroll
            for (int dn = 0; dn < 6; ++dn) {
                short8 fv = *(const short8*)&Vt[(dn * 16 + li) * 76 + kt * 32 + lg * 8];
#pragma unroll
                for (int r = 0; r < 2; ++r)
                    o[r][dn] = MFMA16(fv, pa[r], o[r][dn]);
            }
        }
    }

    // epilogue: lane holds q = r*16+li, d = dn*16 + lg*4 + i -> packed 8B stores
#pragma unroll
    for (int r = 0; r < 2; ++r) {
        const float inv = 1.0f / l_r[r];
        const size_t row = tokBase + qt * 128 + w * 32 + r * 16 + li;
#pragma unroll
        for (int dn = 0; dn < 6; ++dn) {
            short4v ov;
#pragma unroll
            for (int i = 0; i < 4; ++i) ov[i] = f2b(o[r][dn][i] * inv);
            *(short4v*)&O[row * 1536 + h * 96 + dn * 16 + lg * 4] = ov;
        }
    }
}

// ---------------------------------------------------------------------------
extern "C" void kernel_launch(void* const* d_in, const int* in_sizes, int n_in,
                              void* d_out, int out_size, void* d_ws, size_t ws_size,
                              hipStream_t stream) {
    const void* X  = d_in[0];
    const void* Wq = d_in[1];
    const void* bq = d_in[2];
    const void* Wk = d_in[3];
    const void* bk = d_in[4];
    const void* Wv = d_in[5];
    const void* bv = d_in[6];
    const void* qw = d_in[7];
    const void* kw = d_in[8];
    const void* Wo = d_in[9];
    const void* bo = d_in[10];

    char* ws = (char*)d_ws;
    size_t off = 0;
    int* flag = (int*)ws;                      off += 256;
    float* cosT = (float*)(ws + off);          off += 1024 * 96 * 4;
    float* sinT = (float*)(ws + off);          off += 1024 * 96 * 4;
    float* biasqkv = (float*)(ws + off);       off += 4608 * 4;
    float* boc  = (float*)(ws + off);          off += 1536 * 4;
    float* qwc  = (float*)(ws + off);          off += 128 * 4;
    float* kwc  = (float*)(ws + off);          off += 128 * 4;
    off = (off + 255) & ~(size_t)255;
    bf16* Wc  = (bf16*)(ws + off);             off += (size_t)4608 * 1536 * 2;
    bf16* Woc = (bf16*)(ws + off);             off += (size_t)1536 * 1536 * 2;
    bf16* Xc  = (bf16*)(ws + off);             off += (size_t)8192 * 1536 * 2;  // reused as AO
    bf16* Qb  = (bf16*)(ws + off);             off += (size_t)8192 * 1536 * 2;
    bf16* Kb  = (bf16*)(ws + off);             off += (size_t)8192 * 1536 * 2;
    bf16* Vb  = (bf16*)(ws + off);             off += (size_t)8192 * 1536 * 2;
    bf16* AO  = Xc;

    sniff_kernel<<<1, 64, 0, stream>>>((const unsigned*)X, flag);

    canon_x_kernel<<<6144, 256, 0, stream>>>(X, (short*)Xc, 8192 * 1536 / 8, flag);
    canon_w4_kernel<<<dim3(1152, 4), 256, 0, stream>>>(
        Wq, Wk, Wv, Wo,
        (short*)Wc, (short*)(Wc + (size_t)1536 * 1536), (short*)(Wc + (size_t)2 * 1536 * 1536),
        (short*)Woc, flag);
    canon_vec_kernel<<<1, 256, 0, stream>>>(bq, bk, bv, bo, qw, kw,
                                            biasqkv, boc, qwc, kwc, flag);
    rope_tables_kernel<<<384, 256, 0, stream>>>(cosT, sinT);

    gemm256_kernel<<<dim3(18, 32), 512, 0, stream>>>(
        Xc, Wc, biasqkv, Qb, Kb, Vb, 1536, nullptr);

    const float qscale = (float)(0.10206207261596577 * 1.4426950408889634);
    norm_rope_kernel<<<512, 256, 0, stream>>>(Qb, qwc, cosT, sinT, qscale);
    norm_rope_kernel<<<512, 256, 0, stream>>>(Kb, kwc, cosT, sinT, 1.0f);

    attn_kernel<<<1024, 256, 0, stream>>>(Qb, Kb, Vb, AO);

    gemm256_kernel<<<dim3(6, 32), 512, 0, stream>>>(
        AO, Woc, boc, (bf16*)d_out, (bf16*)d_out, (bf16*)d_out, 1536, flag);
}

// Round 7
// 441.516 us; speedup vs baseline: 1.0452x; 1.0452x over previous
//
#include <hip/hip_runtime.h>
#include <hip/hip_bf16.h>
#include <math.h>

typedef __hip_bfloat16 bf16;
typedef __attribute__((ext_vector_type(8))) short short8;
typedef __attribute__((ext_vector_type(4))) short short4v;
typedef __attribute__((ext_vector_type(4))) float f32x4;

#define MFMA16(a, b, c) __builtin_amdgcn_mfma_f32_16x16x32_bf16((a), (b), (c), 0, 0, 0)

typedef const __attribute__((address_space(1))) void GVOID;
typedef __attribute__((address_space(3))) void LVOID;

__device__ __forceinline__ float b2f(short s) {
    union { unsigned u; float f; } v;
    v.u = ((unsigned)(unsigned short)s) << 16;
    return v.f;
}
__device__ __forceinline__ short f2b(float f) {
    union { float f; unsigned u; } v;
    v.f = f;
    unsigned r = v.u + 0x7fffu + ((v.u >> 16) & 1u);
    return (short)(r >> 16);
}
__device__ __forceinline__ unsigned packbf(float a, float b) {
    return ((unsigned)(unsigned short)f2b(a)) | (((unsigned)(unsigned short)f2b(b)) << 16);
}

// ---------------------------------------------------------------------------
// Dtype sniffer (f32 confirmed; deterministic guard).
// ---------------------------------------------------------------------------
__global__ void sniff_kernel(const unsigned* __restrict__ X, int* __restrict__ flag) {
    __shared__ int cnt;
    if (threadIdx.x == 0) cnt = 0;
    __syncthreads();
    int c = 0;
    for (int i = threadIdx.x; i < 256; i += 64) {
        unsigned w = X[i];
        unsigned e = (w >> 7) & 0xFFu;
        c += (e > 140u) ? 1 : 0;
    }
    atomicAdd(&cnt, c);
    __syncthreads();
    if (threadIdx.x == 0) *flag = (cnt >= 16) ? 1 : 0;
}

__device__ __forceinline__ void canon8(const void* src, short* dst, int i, int f) {
    short8 o;
    if (f) {
        const float* s = (const float*)src + (size_t)i * 8;
#pragma unroll
        for (int j = 0; j < 8; ++j) o[j] = f2b(s[j]);
    } else {
        o = ((const short8*)src)[i];
    }
    ((short8*)dst)[i] = o;
}

__global__ __launch_bounds__(256) void canon_x_kernel(
    const void* __restrict__ src, short* __restrict__ dst, int n8,
    const int* __restrict__ flag)
{
    int i = blockIdx.x * 256 + threadIdx.x;
    if (i >= n8) return;
    canon8(src, dst, i, *flag);
}

__global__ __launch_bounds__(256) void canon_w4_kernel(
    const void* __restrict__ s0, const void* __restrict__ s1,
    const void* __restrict__ s2, const void* __restrict__ s3,
    short* __restrict__ d0, short* __restrict__ d1,
    short* __restrict__ d2, short* __restrict__ d3,
    const int* __restrict__ flag)
{
    const int m = blockIdx.y;
    const void* src = (m == 0) ? s0 : (m == 1) ? s1 : (m == 2) ? s2 : s3;
    short* dst = (m == 0) ? d0 : (m == 1) ? d1 : (m == 2) ? d2 : d3;
    int i = blockIdx.x * 256 + threadIdx.x;
    canon8(src, dst, i, *flag);
}

__global__ void canon_vec_kernel(
    const void* __restrict__ bq, const void* __restrict__ bk,
    const void* __restrict__ bv, const void* __restrict__ bo,
    const void* __restrict__ qw, const void* __restrict__ kw,
    float* __restrict__ biasqkv, float* __restrict__ boc,
    float* __restrict__ qwc, float* __restrict__ kwc,
    const int* __restrict__ flag)
{
    const int f = *flag;
    for (int i = threadIdx.x; i < 6336; i += 256) {
        const void* src; float* dst; int j;
        if (i < 4608) {
            int m = i / 1536; j = i - m * 1536;
            src = (m == 0) ? bq : (m == 1) ? bk : bv; dst = biasqkv + i;
        } else if (i < 6144) { j = i - 4608; src = bo; dst = boc + j; }
        else if (i < 6240)   { j = i - 6144; src = qw; dst = qwc + j; }
        else                 { j = i - 6240; src = kw; dst = kwc + j; }
        *dst = f ? ((const float*)src)[j] : b2f(((const short*)src)[j]);
    }
}

// ---------------------------------------------------------------------------
// RoPE tables: cos/sin [1024][96] fp32.
// ---------------------------------------------------------------------------
__global__ void rope_tables_kernel(float* __restrict__ cosT, float* __restrict__ sinT) {
    int idx = blockIdx.x * 256 + threadIdx.x;
    if (idx >= 1024 * 96) return;
    int p = idx / 96;
    int d = idx - p * 96;
    int r = p >> 5, c = p & 31;
    int inRow = (d < 48);
    int dd = inRow ? d : d - 48;
    float pos = inRow ? (float)r : (float)c;
    float ex = -(float)(dd & ~1) / 48.0f;
    float f = powf(10000.0f, ex);
    float ang = pos * f;
    cosT[idx] = cosf(ang);
    sinT[idx] = sinf(ang);
}

// ---------------------------------------------------------------------------
// 256x256 NT GEMM, BK=64 (round-5 structure, measured 169us for QKV):
// full next-tile prefetch at tile top, 4 phases x 16 MFMA, vmcnt(0) drain
// moved before the LAST phase so its 16 MFMAs cover the residual latency,
// one s_barrier per K-tile. LDS XOR-swizzle (0-conflict verified r6 family).
// ---------------------------------------------------------------------------
__global__ __launch_bounds__(512) void gemm256_kernel(
    const bf16* __restrict__ A, const bf16* __restrict__ Bw,
    const float* __restrict__ bias,
    bf16* __restrict__ O0, bf16* __restrict__ O1, bf16* __restrict__ O2,
    int K, const int* __restrict__ outFlag)
{
    __shared__ __align__(16) short As[2][256 * 64];
    __shared__ __align__(16) short Bs[2][256 * 64];

    const int tid = threadIdx.x;
    const int lane = tid & 63, w = tid >> 6;
    const int wm = w >> 2, wn = w & 3;
    const int li = lane & 15, lg = lane >> 4;

    const int total = gridDim.x * gridDim.y;
    const int pp = blockIdx.y * gridDim.x + blockIdx.x;
    const int lb = (pp & 7) * (total >> 3) + (pp >> 3);
    const int nb = lb % gridDim.x;
    const int mb = lb / gridDim.x;
    const long mBase = (long)mb * 256;
    const long nGlob = (long)nb * 256;

    // staging: linear LDS dest L, inverse-swizzled global source S
    const bf16* aSrc[4]; const bf16* bSrc[4]; int ldsOff[4];
#pragma unroll
    for (int u = 0; u < 4; ++u) {
        const int L = u * 8192 + tid * 16;          // byte in 32KB tile
        const int S = L ^ (((L >> 7) & 7) << 4);    // involution
        const int srow = S >> 7;
        const int scol = (S & 127) >> 1;
        aSrc[u] = A + (mBase + srow) * K + scol;
        bSrc[u] = Bw + (nGlob + srow) * K + scol;
        ldsOff[u] = L >> 1;
    }
    const int rxor = (li & 7) << 4;
    int kidx[2];
#pragma unroll
    for (int ks = 0; ks < 2; ++ks)
        kidx[ks] = ((ks * 64 + lg * 16) ^ rxor) >> 1;

    f32x4 acc[8][4] = {};
    const int NT = K >> 6;

    auto stage = [&](int tt, int bb) {
        const long kc = (long)tt * 64;
#pragma unroll
        for (int u = 0; u < 4; ++u)
            __builtin_amdgcn_global_load_lds((GVOID*)(aSrc[u] + kc),
                                             (LVOID*)&As[bb][ldsOff[u]], 16, 0, 0);
#pragma unroll
        for (int u = 0; u < 4; ++u)
            __builtin_amdgcn_global_load_lds((GVOID*)(bSrc[u] + kc),
                                             (LVOID*)&Bs[bb][ldsOff[u]], 16, 0, 0);
    };

    stage(0, 0);
    asm volatile("s_waitcnt vmcnt(0)" ::: "memory");
    __builtin_amdgcn_s_barrier();
    asm volatile("" ::: "memory");

    for (int t = 0; t < NT; ++t) {
        const int cb = t & 1;
        if (t + 1 < NT) stage(t + 1, cb ^ 1);
        const short* Ab = &As[cb][0];
        const short* Bb = &Bs[cb][0];
        short8 fa[4][2], fb[2][2];
#pragma unroll
        for (int ph = 0; ph < 4; ++ph) {
            const int qm = ph >> 1, qn = ph & 1;
            if (qn == 0) {
#pragma unroll
                for (int m = 0; m < 4; ++m) {
                    const int row = wm * 128 + (qm * 4 + m) * 16 + li;
#pragma unroll
                    for (int ks = 0; ks < 2; ++ks)
                        fa[m][ks] = *(const short8*)(Ab + row * 64 + kidx[ks]);
                }
            }
#pragma unroll
            for (int n = 0; n < 2; ++n) {
                const int row = wn * 64 + (qn * 2 + n) * 16 + li;
#pragma unroll
                for (int ks = 0; ks < 2; ++ks)
                    fb[n][ks] = *(const short8*)(Bb + row * 64 + kidx[ks]);
            }
            __builtin_amdgcn_sched_barrier(0);
            __builtin_amdgcn_s_setprio(1);
#pragma unroll
            for (int m = 0; m < 4; ++m)
#pragma unroll
                for (int n = 0; n < 2; ++n)
#pragma unroll
                    for (int ks = 0; ks < 2; ++ks)
                        acc[qm * 4 + m][qn * 2 + n] =
                            MFMA16(fa[m][ks], fb[n][ks], acc[qm * 4 + m][qn * 2 + n]);
            __builtin_amdgcn_s_setprio(0);
            __builtin_amdgcn_sched_barrier(0);
            if (ph == 2)   // drain before last phase: 16 MFMAs cover the residue
                asm volatile("s_waitcnt vmcnt(0)" ::: "memory");
        }
        __builtin_amdgcn_s_barrier();
        asm volatile("" ::: "memory");
    }

    const int f32out = outFlag ? *outFlag : 0;
    const int mat = nb / 6;
    const long colBase = nGlob - (long)mat * 1536;
    bf16* Ob = (mat == 0) ? O0 : (mat == 1) ? O1 : O2;
    if (f32out) {
        float* Cf = (float*)Ob;
#pragma unroll
        for (int n = 0; n < 4; ++n) {
            const long col = colBase + wn * 64 + n * 16 + li;
            const float bv = bias[nGlob + wn * 64 + n * 16 + li];
#pragma unroll
            for (int m = 0; m < 8; ++m) {
                const long row = mBase + wm * 128 + m * 16 + lg * 4;
#pragma unroll
                for (int i = 0; i < 4; ++i)
                    Cf[(row + i) * 1536 + col] = acc[m][n][i] + bv;
            }
        }
    } else {
#pragma unroll
        for (int n = 0; n < 4; ++n) {
            const long col = colBase + wn * 64 + n * 16 + li;
            const float bv = bias[nGlob + wn * 64 + n * 16 + li];
#pragma unroll
            for (int m = 0; m < 8; ++m) {
                const long row = mBase + wm * 128 + m * 16 + lg * 4;
#pragma unroll
                for (int i = 0; i < 4; ++i)
                    Ob[(row + i) * 1536 + col] = __float2bfloat16(acc[m][n][i] + bv);
            }
        }
    }
}

// ---------------------------------------------------------------------------
// 128x128 NT GEMM, BK=64, double-buffered (64KB LDS -> 2 blocks/CU): for the
// out-projection (M=8192,N=1536 -> 768 blocks, 3/CU; the 256^2 kernel only
// made 192 blocks = 0.75/CU and was solo-block latency-bound at 186us).
// Same XOR swizzle family; vmcnt(0)+barrier per tile hidden by co-resident
// block. 4 waves (2x2), per-wave 64x64.
// ---------------------------------------------------------------------------
__global__ __launch_bounds__(256) void gemm128_kernel(
    const bf16* __restrict__ A, const bf16* __restrict__ Bw,
    const float* __restrict__ bias, void* __restrict__ C,
    int K, const int* __restrict__ outFlag)
{
    __shared__ __align__(16) short As[2][128 * 64];
    __shared__ __align__(16) short Bs[2][128 * 64];

    const int tid = threadIdx.x;
    const int lane = tid & 63, w = tid >> 6;
    const int wr = w >> 1, wc = w & 1;
    const int li = lane & 15, lg = lane >> 4;

    const int total = gridDim.x * gridDim.y;
    const int pp = blockIdx.y * gridDim.x + blockIdx.x;
    const int lb = (pp & 7) * (total >> 3) + (pp >> 3);
    const int nb = lb % gridDim.x;
    const int mb = lb / gridDim.x;
    const long mBase = (long)mb * 128;
    const long nBase = (long)nb * 128;

    const bf16* aSrc[4]; const bf16* bSrc[4]; int ldsOff[4];
#pragma unroll
    for (int u = 0; u < 4; ++u) {
        const int L = u * 4096 + tid * 16;          // byte in 16KB tile
        const int S = L ^ (((L >> 7) & 7) << 4);
        const int srow = S >> 7;
        const int scol = (S & 127) >> 1;
        aSrc[u] = A + (mBase + srow) * K + scol;
        bSrc[u] = Bw + (nBase + srow) * K + scol;
        ldsOff[u] = L >> 1;
    }
    const int rxor = (li & 7) << 4;
    int kidx[2];
#pragma unroll
    for (int ks = 0; ks < 2; ++ks)
        kidx[ks] = ((ks * 64 + lg * 16) ^ rxor) >> 1;

    f32x4 acc[4][4] = {};
    const int NT = K >> 6;

    auto stage = [&](int tt, int bb) {
        const long kc = (long)tt * 64;
#pragma unroll
        for (int u = 0; u < 4; ++u)
            __builtin_amdgcn_global_load_lds((GVOID*)(aSrc[u] + kc),
                                             (LVOID*)&As[bb][ldsOff[u]], 16, 0, 0);
#pragma unroll
        for (int u = 0; u < 4; ++u)
            __builtin_amdgcn_global_load_lds((GVOID*)(bSrc[u] + kc),
                                             (LVOID*)&Bs[bb][ldsOff[u]], 16, 0, 0);
    };

    stage(0, 0);
    asm volatile("s_waitcnt vmcnt(0)" ::: "memory");
    __builtin_amdgcn_s_barrier();
    asm volatile("" ::: "memory");

    for (int t = 0; t < NT; ++t) {
        const int cb = t & 1;
        if (t + 1 < NT) stage(t + 1, cb ^ 1);
        const short* Ab = &As[cb][0];
        const short* Bb = &Bs[cb][0];
#pragma unroll
        for (int ks = 0; ks < 2; ++ks) {
            short8 fa[4], fb[4];
#pragma unroll
            for (int m = 0; m < 4; ++m)
                fa[m] = *(const short8*)(Ab + (wr * 64 + m * 16 + li) * 64 + kidx[ks]);
#pragma unroll
            for (int n = 0; n < 4; ++n)
                fb[n] = *(const short8*)(Bb + (wc * 64 + n * 16 + li) * 64 + kidx[ks]);
            __builtin_amdgcn_sched_barrier(0);
            __builtin_amdgcn_s_setprio(1);
#pragma unroll
            for (int m = 0; m < 4; ++m)
#pragma unroll
                for (int n = 0; n < 4; ++n)
                    acc[m][n] = MFMA16(fa[m], fb[n], acc[m][n]);
            __builtin_amdgcn_s_setprio(0);
            __builtin_amdgcn_sched_barrier(0);
        }
        asm volatile("s_waitcnt vmcnt(0)" ::: "memory");
        __builtin_amdgcn_s_barrier();
        asm volatile("" ::: "memory");
    }

    const int f32out = outFlag ? *outFlag : 0;
    if (f32out) {
        float* Cf = (float*)C;
#pragma unroll
        for (int n = 0; n < 4; ++n) {
            const long col = nBase + wc * 64 + n * 16 + li;
            const float bv = bias[col];
#pragma unroll
            for (int m = 0; m < 4; ++m) {
                const long row = mBase + wr * 64 + m * 16 + lg * 4;
#pragma unroll
                for (int i = 0; i < 4; ++i)
                    Cf[(row + i) * 1536 + col] = acc[m][n][i] + bv;
            }
        }
    } else {
        bf16* Cb = (bf16*)C;
#pragma unroll
        for (int n = 0; n < 4; ++n) {
            const long col = nBase + wc * 64 + n * 16 + li;
            const float bv = bias[col];
#pragma unroll
            for (int m = 0; m < 4; ++m) {
                const long row = mBase + wr * 64 + m * 16 + lg * 4;
#pragma unroll
                for (int i = 0; i < 4; ++i)
                    Cb[(row + i) * 1536 + col] = __float2bfloat16(acc[m][n][i] + bv);
            }
        }
    }
}

// ---------------------------------------------------------------------------
// Fused per-head RMSNorm + RoPE, in place (scale folds 1/sqrt(96), +log2e for Q).
// ---------------------------------------------------------------------------
__global__ __launch_bounds__(256) void norm_rope_kernel(
    bf16* __restrict__ T, const float* __restrict__ wgt,
    const float* __restrict__ cosT, const float* __restrict__ sinT,
    float scale)
{
    const int row = blockIdx.x * 256 + threadIdx.x;
    const int tok = row >> 4;
    const int h = row & 15;
    const int spos = tok & 1023;
    bf16* p = T + (size_t)tok * 1536 + h * 96;

    float x[96];
#pragma unroll
    for (int v = 0; v < 12; ++v) {
        short8 t = *(const short8*)(p + v * 8);
#pragma unroll
        for (int j = 0; j < 8; ++j) x[v * 8 + j] = b2f(t[j]);
    }
    float ss = 0.f;
#pragma unroll
    for (int d = 0; d < 96; ++d) ss += x[d] * x[d];
    const float rn = scale / sqrtf(ss * (1.0f / 96.0f) + 1e-6f);

    const float* cr = cosT + spos * 96;
    const float* sr = sinT + spos * 96;

#pragma unroll
    for (int v = 0; v < 12; ++v) {
        short8 o;
#pragma unroll
        for (int j = 0; j < 8; j += 2) {
            const int d = v * 8 + j;
            const float x0 = x[d] * rn * wgt[d];
            const float x1 = x[d + 1] * rn * wgt[d + 1];
            o[j]     = f2b(x0 * cr[d] - x1 * sr[d]);
            o[j + 1] = f2b(x1 * cr[d + 1] + x0 * sr[d + 1]);
        }
        *(short8*)(p + v * 8) = o;
    }
}

// ---------------------------------------------------------------------------
// Flash attention, swapped-operand form (unchanged from round 6; ~35-60us).
// ---------------------------------------------------------------------------
__global__ __launch_bounds__(256) void attn_kernel(
    const bf16* __restrict__ Q, const bf16* __restrict__ K,
    const bf16* __restrict__ V, bf16* __restrict__ O)
{
    __shared__ __align__(16) short Ks[64 * 100];
    __shared__ __align__(16) short Vt[96 * 76];
    __shared__ __align__(16) short Pl[4][32 * 72];

    const int tid = threadIdx.x;
    const int l = tid & 63, w = tid >> 6;
    const int li = l & 15, lg = l >> 4;

    const int p = blockIdx.x;
    const int lb = (p & 7) * 128 + (p >> 3);
    const int qt = lb & 7;
    const int bh = lb >> 3;
    const int b = bh >> 4, h = bh & 15;
    const size_t tokBase = (size_t)b * 1024;

    short8 aq[2][3];
#pragma unroll
    for (int r = 0; r < 2; ++r) {
        const bf16* qp = Q + (tokBase + qt * 128 + w * 32 + r * 16 + li) * 1536 + h * 96;
#pragma unroll
        for (int kk = 0; kk < 3; ++kk)
            aq[r][kk] = *(const short8*)(qp + kk * 32 + lg * 8);
    }

    float m_r[2] = {-1e30f, -1e30f};
    float l_r[2] = {0.f, 0.f};
    f32x4 o[2][6] = {};

    int kr[3], km[3];
#pragma unroll
    for (int u = 0; u < 3; ++u) {
        const int c = tid + 256 * u;
        kr[u] = c / 12;
        km[u] = (c - kr[u] * 12) * 8;
    }
    const int vr = tid >> 2;
    const int vc0 = (tid & 3) * 24;
    short* Plw = &Pl[w][0];

    short8 kreg[3], vreg[3];
#pragma unroll
    for (int u = 0; u < 3; ++u)
        kreg[u] = *(const short8*)(K + (tokBase + kr[u]) * 1536 + h * 96 + km[u]);
    {
        const bf16* vp = V + (tokBase + vr) * 1536 + h * 96 + vc0;
#pragma unroll
        for (int u = 0; u < 3; ++u) vreg[u] = *(const short8*)(vp + u * 8);
    }

    for (int t0 = 0; t0 < 1024; t0 += 64) {
        __syncthreads();
#pragma unroll
        for (int u = 0; u < 3; ++u)
            *(short8*)&Ks[kr[u] * 100 + km[u]] = kreg[u];
#pragma unroll
        for (int u = 0; u < 3; ++u)
#pragma unroll
            for (int j = 0; j < 8; ++j)
                Vt[(vc0 + u * 8 + j) * 76 + vr] = vreg[u][j];
        __syncthreads();

        const int t1 = (t0 + 64 < 1024) ? t0 + 64 : t0;
#pragma unroll
        for (int u = 0; u < 3; ++u)
            kreg[u] = *(const short8*)(K + (tokBase + t1 + kr[u]) * 1536 + h * 96 + km[u]);
        {
            const bf16* vp = V + (tokBase + t1 + vr) * 1536 + h * 96 + vc0;
#pragma unroll
            for (int u = 0; u < 3; ++u) vreg[u] = *(const short8*)(vp + u * 8);
        }

        f32x4 s4[2][4] = {};
#pragma unroll
        for (int kk = 0; kk < 3; ++kk) {
            short8 fk[4];
#pragma unroll
            for (int kn = 0; kn < 4; ++kn)
                fk[kn] = *(const short8*)&Ks[(kn * 16 + li) * 100 + kk * 32 + lg * 8];
#pragma unroll
            for (int r = 0; r < 2; ++r)
#pragma unroll
                for (int kn = 0; kn < 4; ++kn)
                    s4[r][kn] = MFMA16(fk[kn], aq[r][kk], s4[r][kn]);
        }

#pragma unroll
        for (int r = 0; r < 2; ++r) {
            float mk[4];
#pragma unroll
            for (int kn = 0; kn < 4; ++kn)
                mk[kn] = fmaxf(fmaxf(s4[r][kn][0], s4[r][kn][1]),
                               fmaxf(s4[r][kn][2], s4[r][kn][3]));
            float pm = fmaxf(fmaxf(mk[0], mk[1]), fmaxf(mk[2], mk[3]));
            pm = fmaxf(pm, __shfl_xor(pm, 16));
            pm = fmaxf(pm, __shfl_xor(pm, 32));

            float alpha = 1.0f;
            const bool need = (pm > m_r[r] + 8.0f);
            if (need) { alpha = exp2f(m_r[r] - pm); m_r[r] = pm; }
            const float mn = m_r[r];

            float rs = 0.f;
            unsigned pw[8];
#pragma unroll
            for (int kn = 0; kn < 4; ++kn) {
                float p0 = exp2f(s4[r][kn][0] - mn);
                float p1 = exp2f(s4[r][kn][1] - mn);
                float p2 = exp2f(s4[r][kn][2] - mn);
                float p3 = exp2f(s4[r][kn][3] - mn);
                rs += (p0 + p1) + (p2 + p3);
                pw[kn * 2]     = packbf(p0, p1);
                pw[kn * 2 + 1] = packbf(p2, p3);
            }
            rs += __shfl_xor(rs, 16);
            rs += __shfl_xor(rs, 32);
            l_r[r] = l_r[r] * alpha + rs;
            if (need) {
#pragma unroll
                for (int dn = 0; dn < 6; ++dn)
#pragma unroll
                    for (int i = 0; i < 4; ++i) o[r][dn][i] *= alpha;
            }
            unsigned* Pw = (unsigned*)Plw;
            const int rowW = ((r * 16 + li) * 72) >> 1;
#pragma unroll
            for (int kn = 0; kn < 4; ++kn) {
#pragma unroll
                for (int ip = 0; ip < 2; ++ip)
                    Pw[rowW + ((kn * 16 + lg * 4 + ip * 2) >> 1)] = pw[kn * 2 + ip];
            }
        }

#pragma unroll
        for (int kt = 0; kt < 2; ++kt) {
            short8 pa[2];
#pragma unroll
            for (int r = 0; r < 2; ++r)
                pa[r] = *(const short8*)&Plw[(r * 16 + li) * 72 + kt * 32 + lg * 8];
#pragma unroll
            for (int dn = 0; dn < 6; ++dn) {
                short8 fv = *(const short8*)&Vt[(dn * 16 + li) * 76 + kt * 32 + lg * 8];
#pragma unroll
                for (int r = 0; r < 2; ++r)
                    o[r][dn] = MFMA16(fv, pa[r], o[r][dn]);
            }
        }
    }

#pragma unroll
    for (int r = 0; r < 2; ++r) {
        const float inv = 1.0f / l_r[r];
        const size_t row = tokBase + qt * 128 + w * 32 + r * 16 + li;
#pragma unroll
        for (int dn = 0; dn < 6; ++dn) {
            short4v ov;
#pragma unroll
            for (int i = 0; i < 4; ++i) ov[i] = f2b(o[r][dn][i] * inv);
            *(short4v*)&O[row * 1536 + h * 96 + dn * 16 + lg * 4] = ov;
        }
    }
}

// ---------------------------------------------------------------------------
extern "C" void kernel_launch(void* const* d_in, const int* in_sizes, int n_in,
                              void* d_out, int out_size, void* d_ws, size_t ws_size,
                              hipStream_t stream) {
    const void* X  = d_in[0];
    const void* Wq = d_in[1];
    const void* bq = d_in[2];
    const void* Wk = d_in[3];
    const void* bk = d_in[4];
    const void* Wv = d_in[5];
    const void* bv = d_in[6];
    const void* qw = d_in[7];
    const void* kw = d_in[8];
    const void* Wo = d_in[9];
    const void* bo = d_in[10];

    char* ws = (char*)d_ws;
    size_t off = 0;
    int* flag = (int*)ws;                      off += 256;
    float* cosT = (float*)(ws + off);          off += 1024 * 96 * 4;
    float* sinT = (float*)(ws + off);          off += 1024 * 96 * 4;
    float* biasqkv = (float*)(ws + off);       off += 4608 * 4;
    float* boc  = (float*)(ws + off);          off += 1536 * 4;
    float* qwc  = (float*)(ws + off);          off += 128 * 4;
    float* kwc  = (float*)(ws + off);          off += 128 * 4;
    off = (off + 255) & ~(size_t)255;
    bf16* Wc  = (bf16*)(ws + off);             off += (size_t)4608 * 1536 * 2;
    bf16* Woc = (bf16*)(ws + off);             off += (size_t)1536 * 1536 * 2;
    bf16* Xc  = (bf16*)(ws + off);             off += (size_t)8192 * 1536 * 2;  // reused as AO
    bf16* Qb  = (bf16*)(ws + off);             off += (size_t)8192 * 1536 * 2;
    bf16* Kb  = (bf16*)(ws + off);             off += (size_t)8192 * 1536 * 2;
    bf16* Vb  = (bf16*)(ws + off);             off += (size_t)8192 * 1536 * 2;
    bf16* AO  = Xc;

    sniff_kernel<<<1, 64, 0, stream>>>((const unsigned*)X, flag);

    canon_x_kernel<<<6144, 256, 0, stream>>>(X, (short*)Xc, 8192 * 1536 / 8, flag);
    canon_w4_kernel<<<dim3(1152, 4), 256, 0, stream>>>(
        Wq, Wk, Wv, Wo,
        (short*)Wc, (short*)(Wc + (size_t)1536 * 1536), (short*)(Wc + (size_t)2 * 1536 * 1536),
        (short*)Woc, flag);
    canon_vec_kernel<<<1, 256, 0, stream>>>(bq, bk, bv, bo, qw, kw,
                                            biasqkv, boc, qwc, kwc, flag);
    rope_tables_kernel<<<384, 256, 0, stream>>>(cosT, sinT);

    gemm256_kernel<<<dim3(18, 32), 512, 0, stream>>>(
        Xc, Wc, biasqkv, Qb, Kb, Vb, 1536, nullptr);

    const float qscale = (float)(0.10206207261596577 * 1.4426950408889634);
    norm_rope_kernel<<<512, 256, 0, stream>>>(Qb, qwc, cosT, sinT, qscale);
    norm_rope_kernel<<<512, 256, 0, stream>>>(Kb, kwc, cosT, sinT, 1.0f);

    attn_kernel<<<1024, 256, 0, stream>>>(Qb, Kb, Vb, AO);

    gemm128_kernel<<<dim3(12, 64), 256, 0, stream>>>(
        AO, Woc, boc, d_out, 1536, flag);
}

// Round 8
// 384.687 us; speedup vs baseline: 1.1997x; 1.1477x over previous
//
#include <hip/hip_runtime.h>
#include <hip/hip_bf16.h>
#include <math.h>

typedef __hip_bfloat16 bf16;
typedef __attribute__((ext_vector_type(8))) short short8;
typedef __attribute__((ext_vector_type(4))) short short4v;
typedef __attribute__((ext_vector_type(4))) float f32x4;

#define MFMA16(a, b, c) __builtin_amdgcn_mfma_f32_16x16x32_bf16((a), (b), (c), 0, 0, 0)

typedef const __attribute__((address_space(1))) void GVOID;
typedef __attribute__((address_space(3))) void LVOID;

__device__ __forceinline__ float b2f(short s) {
    union { unsigned u; float f; } v;
    v.u = ((unsigned)(unsigned short)s) << 16;
    return v.f;
}
__device__ __forceinline__ short f2b(float f) {
    union { float f; unsigned u; } v;
    v.f = f;
    unsigned r = v.u + 0x7fffu + ((v.u >> 16) & 1u);
    return (short)(r >> 16);
}
__device__ __forceinline__ unsigned packbf2(float a, float b) {
    float2 t; t.x = a; t.y = b;
    __hip_bfloat162 h = __float22bfloat162_rn(t);   // -> v_cvt_pk_bf16_f32
    union { __hip_bfloat162 h; unsigned u; } cv; cv.h = h;
    return cv.u;
}
__device__ __forceinline__ short bf2s(float x) {
    __hip_bfloat16 h = __float2bfloat16(x);
    union { __hip_bfloat16 h; short s; } cv; cv.h = h;
    return cv.s;
}

// ---------------------------------------------------------------------------
// Dtype sniffer (f32 confirmed; deterministic guard).
// ---------------------------------------------------------------------------
__global__ void sniff_kernel(const unsigned* __restrict__ X, int* __restrict__ flag) {
    __shared__ int cnt;
    if (threadIdx.x == 0) cnt = 0;
    __syncthreads();
    int c = 0;
    for (int i = threadIdx.x; i < 256; i += 64) {
        unsigned w = X[i];
        unsigned e = (w >> 7) & 0xFFu;
        c += (e > 140u) ? 1 : 0;
    }
    atomicAdd(&cnt, c);
    __syncthreads();
    if (threadIdx.x == 0) *flag = (cnt >= 16) ? 1 : 0;
}

__device__ __forceinline__ void canon8(const void* src, short* dst, int i, int f) {
    short8 o;
    if (f) {
        const float* s = (const float*)src + (size_t)i * 8;
#pragma unroll
        for (int j = 0; j < 8; ++j) o[j] = f2b(s[j]);
    } else {
        o = ((const short8*)src)[i];
    }
    ((short8*)dst)[i] = o;
}

__global__ __launch_bounds__(256) void canon_x_kernel(
    const void* __restrict__ src, short* __restrict__ dst, int n8,
    const int* __restrict__ flag)
{
    int i = blockIdx.x * 256 + threadIdx.x;
    if (i >= n8) return;
    canon8(src, dst, i, *flag);
}

__global__ __launch_bounds__(256) void canon_w4_kernel(
    const void* __restrict__ s0, const void* __restrict__ s1,
    const void* __restrict__ s2, const void* __restrict__ s3,
    short* __restrict__ d0, short* __restrict__ d1,
    short* __restrict__ d2, short* __restrict__ d3,
    const int* __restrict__ flag)
{
    const int m = blockIdx.y;
    const void* src = (m == 0) ? s0 : (m == 1) ? s1 : (m == 2) ? s2 : s3;
    short* dst = (m == 0) ? d0 : (m == 1) ? d1 : (m == 2) ? d2 : d3;
    int i = blockIdx.x * 256 + threadIdx.x;
    canon8(src, dst, i, *flag);
}

__global__ void canon_vec_kernel(
    const void* __restrict__ bq, const void* __restrict__ bk,
    const void* __restrict__ bv, const void* __restrict__ bo,
    const void* __restrict__ qw, const void* __restrict__ kw,
    float* __restrict__ biasqkv, float* __restrict__ boc,
    float* __restrict__ qwc, float* __restrict__ kwc,
    const int* __restrict__ flag)
{
    const int f = *flag;
    for (int i = threadIdx.x; i < 6336; i += 256) {
        const void* src; float* dst; int j;
        if (i < 4608) {
            int m = i / 1536; j = i - m * 1536;
            src = (m == 0) ? bq : (m == 1) ? bk : bv; dst = biasqkv + i;
        } else if (i < 6144) { j = i - 4608; src = bo; dst = boc + j; }
        else if (i < 6240)   { j = i - 6144; src = qw; dst = qwc + j; }
        else                 { j = i - 6240; src = kw; dst = kwc + j; }
        *dst = f ? ((const float*)src)[j] : b2f(((const short*)src)[j]);
    }
}

// ---------------------------------------------------------------------------
// RoPE tables: cos/sin [1024][96] fp32.
// ---------------------------------------------------------------------------
__global__ void rope_tables_kernel(float* __restrict__ cosT, float* __restrict__ sinT) {
    int idx = blockIdx.x * 256 + threadIdx.x;
    if (idx >= 1024 * 96) return;
    int p = idx / 96;
    int d = idx - p * 96;
    int r = p >> 5, c = p & 31;
    int inRow = (d < 48);
    int dd = inRow ? d : d - 48;
    float pos = inRow ? (float)r : (float)c;
    float ex = -(float)(dd & ~1) / 48.0f;
    float f = powf(10000.0f, ex);
    float ang = pos * f;
    cosT[idx] = cosf(ang);
    sinT[idx] = sinf(ang);
}

// ---------------------------------------------------------------------------
// 128x128 NT GEMM, BK=64, double-buffered (64KB LDS -> 2 blocks/CU). Measured
// ~860 TF on the out-projection (r7) -> now used for QKV too (2304 blocks,
// 9/CU). 3-way output split (mat = nb/12). XOR swizzle family (0-conflict),
// vmcnt(0)+barrier per tile hidden by co-resident blocks. 4 waves, 64x64 each.
// ---------------------------------------------------------------------------
__global__ __launch_bounds__(256) void gemm128_kernel(
    const bf16* __restrict__ A, const bf16* __restrict__ Bw,
    const float* __restrict__ bias,
    bf16* __restrict__ O0, bf16* __restrict__ O1, bf16* __restrict__ O2,
    int K, const int* __restrict__ outFlag)
{
    __shared__ __align__(16) short As[2][128 * 64];
    __shared__ __align__(16) short Bs[2][128 * 64];

    const int tid = threadIdx.x;
    const int lane = tid & 63, w = tid >> 6;
    const int wr = w >> 1, wc = w & 1;
    const int li = lane & 15, lg = lane >> 4;

    const int total = gridDim.x * gridDim.y;
    const int pp = blockIdx.y * gridDim.x + blockIdx.x;
    const int lb = (pp & 7) * (total >> 3) + (pp >> 3);
    const int nb = lb % gridDim.x;
    const int mb = lb / gridDim.x;
    const long mBase = (long)mb * 128;
    const long nGlob = (long)nb * 128;

    const bf16* aSrc[4]; const bf16* bSrc[4]; int ldsOff[4];
#pragma unroll
    for (int u = 0; u < 4; ++u) {
        const int L = u * 4096 + tid * 16;          // byte in 16KB tile
        const int S = L ^ (((L >> 7) & 7) << 4);
        const int srow = S >> 7;
        const int scol = (S & 127) >> 1;
        aSrc[u] = A + (mBase + srow) * K + scol;
        bSrc[u] = Bw + (nGlob + srow) * K + scol;
        ldsOff[u] = L >> 1;
    }
    const int rxor = (li & 7) << 4;
    int kidx[2];
#pragma unroll
    for (int ks = 0; ks < 2; ++ks)
        kidx[ks] = ((ks * 64 + lg * 16) ^ rxor) >> 1;

    f32x4 acc[4][4] = {};
    const int NT = K >> 6;

    auto stage = [&](int tt, int bb) {
        const long kc = (long)tt * 64;
#pragma unroll
        for (int u = 0; u < 4; ++u)
            __builtin_amdgcn_global_load_lds((GVOID*)(aSrc[u] + kc),
                                             (LVOID*)&As[bb][ldsOff[u]], 16, 0, 0);
#pragma unroll
        for (int u = 0; u < 4; ++u)
            __builtin_amdgcn_global_load_lds((GVOID*)(bSrc[u] + kc),
                                             (LVOID*)&Bs[bb][ldsOff[u]], 16, 0, 0);
    };

    stage(0, 0);
    asm volatile("s_waitcnt vmcnt(0)" ::: "memory");
    __builtin_amdgcn_s_barrier();
    asm volatile("" ::: "memory");

    for (int t = 0; t < NT; ++t) {
        const int cb = t & 1;
        if (t + 1 < NT) stage(t + 1, cb ^ 1);
        const short* Ab = &As[cb][0];
        const short* Bb = &Bs[cb][0];
#pragma unroll
        for (int ks = 0; ks < 2; ++ks) {
            short8 fa[4], fb[4];
#pragma unroll
            for (int m = 0; m < 4; ++m)
                fa[m] = *(const short8*)(Ab + (wr * 64 + m * 16 + li) * 64 + kidx[ks]);
#pragma unroll
            for (int n = 0; n < 4; ++n)
                fb[n] = *(const short8*)(Bb + (wc * 64 + n * 16 + li) * 64 + kidx[ks]);
            __builtin_amdgcn_sched_barrier(0);
            __builtin_amdgcn_s_setprio(1);
#pragma unroll
            for (int m = 0; m < 4; ++m)
#pragma unroll
                for (int n = 0; n < 4; ++n)
                    acc[m][n] = MFMA16(fa[m], fb[n], acc[m][n]);
            __builtin_amdgcn_s_setprio(0);
            __builtin_amdgcn_sched_barrier(0);
        }
        asm volatile("s_waitcnt vmcnt(0)" ::: "memory");
        __builtin_amdgcn_s_barrier();
        asm volatile("" ::: "memory");
    }

    const int f32out = outFlag ? *outFlag : 0;
    const int mat = nb / 12;                 // 0..2 for QKV; 0 for N=1536 grids
    const long colBase = nGlob - (long)mat * 1536;
    bf16* Ob = (mat == 0) ? O0 : (mat == 1) ? O1 : O2;
    if (f32out) {
        float* Cf = (float*)Ob;
#pragma unroll
        for (int n = 0; n < 4; ++n) {
            const long col = colBase + wc * 64 + n * 16 + li;
            const float bv = bias[nGlob + wc * 64 + n * 16 + li];
#pragma unroll
            for (int m = 0; m < 4; ++m) {
                const long row = mBase + wr * 64 + m * 16 + lg * 4;
#pragma unroll
                for (int i = 0; i < 4; ++i)
                    Cf[(row + i) * 1536 + col] = acc[m][n][i] + bv;
            }
        }
    } else {
#pragma unroll
        for (int n = 0; n < 4; ++n) {
            const long col = colBase + wc * 64 + n * 16 + li;
            const float bv = bias[nGlob + wc * 64 + n * 16 + li];
#pragma unroll
            for (int m = 0; m < 4; ++m) {
                const long row = mBase + wr * 64 + m * 16 + lg * 4;
#pragma unroll
                for (int i = 0; i < 4; ++i)
                    Ob[(row + i) * 1536 + col] = __float2bfloat16(acc[m][n][i] + bv);
            }
        }
    }
}

// ---------------------------------------------------------------------------
// Fused per-head RMSNorm + RoPE, in place (scale folds 1/sqrt(96), +log2e for Q).
// ---------------------------------------------------------------------------
__global__ __launch_bounds__(256) void norm_rope_kernel(
    bf16* __restrict__ T, const float* __restrict__ wgt,
    const float* __restrict__ cosT, const float* __restrict__ sinT,
    float scale)
{
    const int row = blockIdx.x * 256 + threadIdx.x;
    const int tok = row >> 4;
    const int h = row & 15;
    const int spos = tok & 1023;
    bf16* p = T + (size_t)tok * 1536 + h * 96;

    float x[96];
#pragma unroll
    for (int v = 0; v < 12; ++v) {
        short8 t = *(const short8*)(p + v * 8);
#pragma unroll
        for (int j = 0; j < 8; ++j) x[v * 8 + j] = b2f(t[j]);
    }
    float ss = 0.f;
#pragma unroll
    for (int d = 0; d < 96; ++d) ss += x[d] * x[d];
    const float rn = scale / sqrtf(ss * (1.0f / 96.0f) + 1e-6f);

    const float* cr = cosT + spos * 96;
    const float* sr = sinT + spos * 96;

#pragma unroll
    for (int v = 0; v < 12; ++v) {
        short8 o;
#pragma unroll
        for (int j = 0; j < 8; j += 2) {
            const int d = v * 8 + j;
            const float x0 = x[d] * rn * wgt[d];
            const float x1 = x[d + 1] * rn * wgt[d + 1];
            o[j]     = f2b(x0 * cr[d] - x1 * sr[d]);
            o[j + 1] = f2b(x1 * cr[d + 1] + x0 * sr[d + 1]);
        }
        *(short8*)(p + v * 8) = o;
    }
}

// ---------------------------------------------------------------------------
// Flash attention, swapped-operand form. Round-8 fixes: Ks stride 104 (2-way
// read windows = free, was 100 -> overlapping), V^T staged via token-pair
// packed b32 writes (was 8-way-conflicted scalar b16), cvt_pk bf16 packing.
// ---------------------------------------------------------------------------
__global__ __launch_bounds__(256) void attn_kernel(
    const bf16* __restrict__ Q, const bf16* __restrict__ K,
    const bf16* __restrict__ V, bf16* __restrict__ O)
{
    __shared__ __align__(16) short Ks[64 * 104];
    __shared__ __align__(16) short Vt[96 * 76];
    __shared__ __align__(16) short Pl[4][32 * 72];

    const int tid = threadIdx.x;
    const int l = tid & 63, w = tid >> 6;
    const int li = l & 15, lg = l >> 4;

    const int p = blockIdx.x;
    const int lb = (p & 7) * 128 + (p >> 3);
    const int qt = lb & 7;
    const int bh = lb >> 3;
    const int b = bh >> 4, h = bh & 15;
    const size_t tokBase = (size_t)b * 1024;

    short8 aq[2][3];
#pragma unroll
    for (int r = 0; r < 2; ++r) {
        const bf16* qp = Q + (tokBase + qt * 128 + w * 32 + r * 16 + li) * 1536 + h * 96;
#pragma unroll
        for (int kk = 0; kk < 3; ++kk)
            aq[r][kk] = *(const short8*)(qp + kk * 32 + lg * 8);
    }

    float m_r[2] = {-1e30f, -1e30f};
    float l_r[2] = {0.f, 0.f};
    f32x4 o[2][6] = {};

    // K staging map: 768 16B chunks, 3 per thread
    int kr[3], km[3];
#pragma unroll
    for (int u = 0; u < 3; ++u) {
        const int c = tid + 256 * u;
        kr[u] = c / 12;
        km[u] = (c - kr[u] * 12) * 8;
    }
    // V staging map: thread = (token-pair t2, d-block dh of 12)
    const int t2 = tid >> 3;
    const int dh = tid & 7;
    const bf16* vbase = V + (tokBase + 2 * t2) * 1536 + h * 96 + dh * 12;
    short* Plw = &Pl[w][0];

    // T14 prologue: tile 0 into regs
    short8 kreg[3];
    short4v vr0[3], vr1[3];
#pragma unroll
    for (int u = 0; u < 3; ++u)
        kreg[u] = *(const short8*)(K + (tokBase + kr[u]) * 1536 + h * 96 + km[u]);
#pragma unroll
    for (int u = 0; u < 3; ++u) {
        vr0[u] = *(const short4v*)(vbase + u * 4);
        vr1[u] = *(const short4v*)(vbase + 1536 + u * 4);
    }

    for (int t0 = 0; t0 < 1024; t0 += 64) {
        __syncthreads();   // prior tile's LDS reads done
        // reg -> LDS
#pragma unroll
        for (int u = 0; u < 3; ++u)
            *(short8*)&Ks[kr[u] * 104 + km[u]] = kreg[u];
        {
            unsigned* Vt32 = (unsigned*)Vt;
#pragma unroll
            for (int u = 0; u < 3; ++u)
#pragma unroll
                for (int j = 0; j < 4; ++j) {
                    const int d = dh * 12 + u * 4 + j;
                    const unsigned pk = ((unsigned)(unsigned short)vr0[u][j]) |
                                        (((unsigned)(unsigned short)vr1[u][j]) << 16);
                    Vt32[d * 38 + t2] = pk;
                }
        }
        __syncthreads();

        // issue next tile's global loads (covered by compute below)
        const int t1 = (t0 + 64 < 1024) ? t0 + 64 : t0;
#pragma unroll
        for (int u = 0; u < 3; ++u)
            kreg[u] = *(const short8*)(K + (tokBase + t1 + kr[u]) * 1536 + h * 96 + km[u]);
        {
            const bf16* vp = vbase + (size_t)t1 * 1536;
#pragma unroll
            for (int u = 0; u < 3; ++u) {
                vr0[u] = *(const short4v*)(vp + u * 4);
                vr1[u] = *(const short4v*)(vp + 1536 + u * 4);
            }
        }

        // S^T[key][q]: key rows, q = li cols
        f32x4 s4[2][4] = {};
#pragma unroll
        for (int kk = 0; kk < 3; ++kk) {
            short8 fk[4];
#pragma unroll
            for (int kn = 0; kn < 4; ++kn)
                fk[kn] = *(const short8*)&Ks[(kn * 16 + li) * 104 + kk * 32 + lg * 8];
#pragma unroll
            for (int r = 0; r < 2; ++r)
#pragma unroll
                for (int kn = 0; kn < 4; ++kn)
                    s4[r][kn] = MFMA16(fk[kn], aq[r][kk], s4[r][kn]);
        }

        // softmax: per lane 16 local keys; cross-lg reduce via xor 16/32
#pragma unroll
        for (int r = 0; r < 2; ++r) {
            float mk[4];
#pragma unroll
            for (int kn = 0; kn < 4; ++kn)
                mk[kn] = fmaxf(fmaxf(s4[r][kn][0], s4[r][kn][1]),
                               fmaxf(s4[r][kn][2], s4[r][kn][3]));
            float pm = fmaxf(fmaxf(mk[0], mk[1]), fmaxf(mk[2], mk[3]));
            pm = fmaxf(pm, __shfl_xor(pm, 16));
            pm = fmaxf(pm, __shfl_xor(pm, 32));

            float alpha = 1.0f;
            const bool need = (pm > m_r[r] + 8.0f);
            if (need) { alpha = exp2f(m_r[r] - pm); m_r[r] = pm; }
            const float mn = m_r[r];

            float rs = 0.f;
            unsigned pw[8];
#pragma unroll
            for (int kn = 0; kn < 4; ++kn) {
                float p0 = exp2f(s4[r][kn][0] - mn);
                float p1 = exp2f(s4[r][kn][1] - mn);
                float p2 = exp2f(s4[r][kn][2] - mn);
                float p3 = exp2f(s4[r][kn][3] - mn);
                rs += (p0 + p1) + (p2 + p3);
                pw[kn * 2]     = packbf2(p0, p1);
                pw[kn * 2 + 1] = packbf2(p2, p3);
            }
            rs += __shfl_xor(rs, 16);
            rs += __shfl_xor(rs, 32);
            l_r[r] = l_r[r] * alpha + rs;
            if (need) {
#pragma unroll
                for (int dn = 0; dn < 6; ++dn)
#pragma unroll
                    for (int i = 0; i < 4; ++i) o[r][dn][i] *= alpha;
            }
            unsigned* Pw = (unsigned*)Plw;
            const int rowW = ((r * 16 + li) * 72) >> 1;
#pragma unroll
            for (int kn = 0; kn < 4; ++kn) {
#pragma unroll
                for (int ip = 0; ip < 2; ++ip)
                    Pw[rowW + ((kn * 16 + lg * 4 + ip * 2) >> 1)] = pw[kn * 2 + ip];
            }
        }

        // O^T += V^T * P^T
#pragma unroll
        for (int kt = 0; kt < 2; ++kt) {
            short8 pa[2];
#pragma unroll
            for (int r = 0; r < 2; ++r)
                pa[r] = *(const short8*)&Plw[(r * 16 + li) * 72 + kt * 32 + lg * 8];
#pragma unroll
            for (int dn = 0; dn < 6; ++dn) {
                short8 fv = *(const short8*)&Vt[(dn * 16 + li) * 76 + kt * 32 + lg * 8];
#pragma unroll
                for (int r = 0; r < 2; ++r)
                    o[r][dn] = MFMA16(fv, pa[r], o[r][dn]);
            }
        }
    }

    // epilogue: lane holds q = r*16+li, d = dn*16 + lg*4 + i
#pragma unroll
    for (int r = 0; r < 2; ++r) {
        const float inv = 1.0f / l_r[r];
        const size_t row = tokBase + qt * 128 + w * 32 + r * 16 + li;
#pragma unroll
        for (int dn = 0; dn < 6; ++dn) {
            short4v ov;
#pragma unroll
            for (int i = 0; i < 4; ++i) ov[i] = bf2s(o[r][dn][i] * inv);
            *(short4v*)&O[row * 1536 + h * 96 + dn * 16 + lg * 4] = ov;
        }
    }
}

// ---------------------------------------------------------------------------
extern "C" void kernel_launch(void* const* d_in, const int* in_sizes, int n_in,
                              void* d_out, int out_size, void* d_ws, size_t ws_size,
                              hipStream_t stream) {
    const void* X  = d_in[0];
    const void* Wq = d_in[1];
    const void* bq = d_in[2];
    const void* Wk = d_in[3];
    const void* bk = d_in[4];
    const void* Wv = d_in[5];
    const void* bv = d_in[6];
    const void* qw = d_in[7];
    const void* kw = d_in[8];
    const void* Wo = d_in[9];
    const void* bo = d_in[10];

    char* ws = (char*)d_ws;
    size_t off = 0;
    int* flag = (int*)ws;                      off += 256;
    float* cosT = (float*)(ws + off);          off += 1024 * 96 * 4;
    float* sinT = (float*)(ws + off);          off += 1024 * 96 * 4;
    float* biasqkv = (float*)(ws + off);       off += 4608 * 4;
    float* boc  = (float*)(ws + off);          off += 1536 * 4;
    float* qwc  = (float*)(ws + off);          off += 128 * 4;
    float* kwc  = (float*)(ws + off);          off += 128 * 4;
    off = (off + 255) & ~(size_t)255;
    bf16* Wc  = (bf16*)(ws + off);             off += (size_t)4608 * 1536 * 2;
    bf16* Woc = (bf16*)(ws + off);             off += (size_t)1536 * 1536 * 2;
    bf16* Xc  = (bf16*)(ws + off);             off += (size_t)8192 * 1536 * 2;  // reused as AO
    bf16* Qb  = (bf16*)(ws + off);             off += (size_t)8192 * 1536 * 2;
    bf16* Kb  = (bf16*)(ws + off);             off += (size_t)8192 * 1536 * 2;
    bf16* Vb  = (bf16*)(ws + off);             off += (size_t)8192 * 1536 * 2;
    bf16* AO  = Xc;

    sniff_kernel<<<1, 64, 0, stream>>>((const unsigned*)X, flag);

    canon_x_kernel<<<6144, 256, 0, stream>>>(X, (short*)Xc, 8192 * 1536 / 8, flag);
    canon_w4_kernel<<<dim3(1152, 4), 256, 0, stream>>>(
        Wq, Wk, Wv, Wo,
        (short*)Wc, (short*)(Wc + (size_t)1536 * 1536), (short*)(Wc + (size_t)2 * 1536 * 1536),
        (short*)Woc, flag);
    canon_vec_kernel<<<1, 256, 0, stream>>>(bq, bk, bv, bo, qw, kw,
                                            biasqkv, boc, qwc, kwc, flag);
    rope_tables_kernel<<<384, 256, 0, stream>>>(cosT, sinT);

    // fused QKV projection: [8192,4608] = Xc @ Wc^T + biasqkv -> Qb|Kb|Vb
    gemm128_kernel<<<dim3(36, 64), 256, 0, stream>>>(
        Xc, Wc, biasqkv, Qb, Kb, Vb, 1536, nullptr);

    const float qscale = (float)(0.10206207261596577 * 1.4426950408889634);
    norm_rope_kernel<<<512, 256, 0, stream>>>(Qb, qwc, cosT, sinT, qscale);
    norm_rope_kernel<<<512, 256, 0, stream>>>(Kb, kwc, cosT, sinT, 1.0f);

    attn_kernel<<<1024, 256, 0, stream>>>(Qb, Kb, Vb, AO);

    gemm128_kernel<<<dim3(12, 64), 256, 0, stream>>>(
        AO, Woc, boc, (bf16*)d_out, (bf16*)d_out, (bf16*)d_out, 1536, flag);
}